// Round 1
// baseline (549.534 us; speedup 1.0000x reference)
//
#include <hip/hip_runtime.h>

// out[b,i,j] = alpha_i * max(sq_i + sq_j - 2*(p_i.p_j) + along^2*(tnorm2_i - 2), 0)
//            + beta_i * along^2
// along = (p_i . t_i) - (p_j . t_i)
// alpha_i = 2*(1+lin_i), beta_i = 0.5*(1-lin_i)
//
// Write-bound: 512 MiB fp32 output; inputs ~460 KiB (L2-resident).
// One thread -> 4 consecutive j, float4 store. Row scalars are blockIdx-uniform.

__global__ __launch_bounds__(256) void AnisotropicDistance_kernel(
    const float* __restrict__ points,
    const float* __restrict__ pdir,
    const float* __restrict__ lin,
    float* __restrict__ out,
    int N)
{
    const int b  = blockIdx.z;
    const int i  = blockIdx.y;
    const int j0 = (blockIdx.x * blockDim.x + threadIdx.x) * 4;
    if (j0 >= N) return;

    const float* pb = points + (size_t)b * N * 3;
    const float* tb = pdir   + (size_t)b * N * 3;

    // Row-uniform scalars (blockIdx-derived -> scalar loads)
    const float pix = pb[(size_t)i*3 + 0];
    const float piy = pb[(size_t)i*3 + 1];
    const float piz = pb[(size_t)i*3 + 2];
    const float tix = tb[(size_t)i*3 + 0];
    const float tiy = tb[(size_t)i*3 + 1];
    const float tiz = tb[(size_t)i*3 + 2];
    const float l   = lin[(size_t)b * N + i];

    const float pdself = pix*tix + piy*tiy + piz*tiz;   // p_i . t_i
    const float sqi    = pix*pix + piy*piy + piz*piz;   // ||p_i||^2
    const float tn2m2  = (tix*tix + tiy*tiy + tiz*tiz) - 2.0f;
    const float alpha  = 2.0f * (1.0f + l);
    const float beta   = 0.5f * (1.0f - l);

    // 4 points for j0..j0+3: 12 contiguous floats, 16B-aligned (j0 % 4 == 0)
    const float4* pj4 = (const float4*)(pb + (size_t)j0 * 3);
    const float4 a0 = pj4[0];
    const float4 a1 = pj4[1];
    const float4 a2 = pj4[2];

    const float px[4] = {a0.x, a0.w, a1.z, a2.y};
    const float py[4] = {a0.y, a1.x, a1.w, a2.z};
    const float pz[4] = {a0.z, a1.y, a2.x, a2.w};

    float4 res;
    float* r = (float*)&res;
#pragma unroll
    for (int k = 0; k < 4; ++k) {
        const float dotp   = px[k]*pix + py[k]*piy + pz[k]*piz;   // p_j . p_i
        const float dott   = px[k]*tix + py[k]*tiy + pz[k]*tiz;   // p_j . t_i
        const float along  = pdself - dott;
        const float along2 = along * along;
        const float sqj    = px[k]*px[k] + py[k]*py[k] + pz[k]*pz[k];
        const float sqd    = sqi + sqj - 2.0f * dotp;
        const float normal = fmaxf(fmaf(along2, tn2m2, sqd), 0.0f);
        r[k] = fmaf(alpha, normal, beta * along2);
    }

    *(float4*)(out + ((size_t)b * N + (size_t)i) * N + j0) = res;
}

extern "C" void kernel_launch(void* const* d_in, const int* in_sizes, int n_in,
                              void* d_out, int out_size, void* d_ws, size_t ws_size,
                              hipStream_t stream)
{
    const float* points = (const float*)d_in[0];
    const float* pdir   = (const float*)d_in[1];
    const float* lin    = (const float*)d_in[2];
    float* out = (float*)d_out;

    const long long BN = in_sizes[2];              // B*N  (linearity has 1 elem per point)
    const long long N  = (long long)out_size / BN; // out = B*N*N
    const int B = (int)(BN / N);

    const int threads = 256;
    const int jblocks = (int)((N + (long long)threads * 4 - 1) / ((long long)threads * 4));
    dim3 grid(jblocks, (unsigned)N, (unsigned)B);
    AnisotropicDistance_kernel<<<grid, threads, 0, stream>>>(points, pdir, lin, out, (int)N);
}